// Round 7
// baseline (164.999 us; speedup 1.0000x reference)
//
#include <hip/hip_runtime.h>

// Network_49873160241834: fused LIF scan (B=256,F=10,C=3,T=8192) + conv(c) + linear(f).
//
// Speculative time-chunking: 64 chunks x 128 steps, 128-step v=0 warmup (LIF resets v
// to EXACTLY +0 on spike => warmup converges bit-exactly; WARM=128 validated R3-R5).
// Grid (B,16), 64 thr/block = 4096 waves (~13 blocks/CU, LDS-capped). Block cb owns
// chunks 4cb..4cb+3: half h lane runs chains v0 -> chunk 4cb+2h, v1 -> chunk 4cb+2h+1.
//
// R7 fixes vs R6 (absmax 13 => staged x / LDS garbage, from unproven offset semantics
// and mixed load+store vmcnt ordering):
//  - global_load_lds offset arg = 0; stage offsets are pointer arithmetic (compiler
//    folds into the instruction offset field with correct semantics).
//  - outputs buffered in 16 VGPRs, stored once at the end -> vm queue is LOADS ONLY,
//    so waitvm<5> is exact under the loads-return-in-order guarantee.
// Staging: per 32-step stage the wave issues 5 async global->LDS dwordx4 ops
// (40 streams x 32 floats = 5 KB), double-buffered; piece permutation (lane piece
// p=(q&7)^(s&7)) gives 128B-coalesced global reads and <=2-way LDS read conflicts.
//
// EXACTNESS: v-update is separately-rounded f32 (no FMA); spike decisions must match
// numpy f32 bit-exactly (one flip costs ~0.5 in out; threshold 0.096).

#define T_LEN 8192
#define NF 10
#define CHUNK 128
#define WARM 128
#define CPB 4
#define GRIDY 16        // 64 chunks / 4 per block
#define BUFW 1280       // words per LDS buffer: 40 streams * 32 floats

typedef const __attribute__((address_space(1))) void gld_gv;
typedef __attribute__((address_space(3))) void gld_lv;

template<int N> __device__ __forceinline__ void waitvm() {
  asm volatile("s_waitcnt vmcnt(%0)" :: "i"(N) : "memory");
}

// 5 async global->LDS loads: slot q=i*64+lane -> LDS words [4q,4q+4).
// Stream s=q>>3 piece p=q&7 holds global piece g=p^(s&7) (XOR swizzle).
__device__ __forceinline__ void stage_loads(const float* g0, const float* g1,
                                            const float* g2, const float* g3,
                                            const float* g4, float* lb) {
  __builtin_amdgcn_global_load_lds((gld_gv*)g0, (gld_lv*)(lb       ), 16, 0, 0);
  __builtin_amdgcn_global_load_lds((gld_gv*)g1, (gld_lv*)(lb +  256), 16, 0, 0);
  __builtin_amdgcn_global_load_lds((gld_gv*)g2, (gld_lv*)(lb +  512), 16, 0, 0);
  __builtin_amdgcn_global_load_lds((gld_gv*)g3, (gld_lv*)(lb +  768), 16, 0, 0);
  __builtin_amdgcn_global_load_lds((gld_gv*)g4, (gld_lv*)(lb + 1024), 16, 0, 0);
}

// 32 LIF steps for two independent chains; MAIN also captures spike masks:
// lane (o,tt) latches all 4 chunk masks at step t==tt from the wave-uniform ballots.
template<bool MAIN>
__device__ __forceinline__ void run32(const float* pA, const float* pB,
                                      int fxA, int fxB, float k, float vt, int tt,
                                      float& v0, float& v1,
                                      unsigned& m0, unsigned& m1,
                                      unsigned& m2, unsigned& m3) {
#pragma unroll
  for (int g = 0; g < 8; ++g) {
    float4 qa = *(const float4*)(pA + ((g << 2) ^ fxA));
    float4 qb = *(const float4*)(pB + ((g << 2) ^ fxB));
    float xa[4] = {qa.x, qa.y, qa.z, qa.w};
    float xb[4] = {qb.x, qb.y, qb.z, qb.w};
#pragma unroll
    for (int r = 0; r < 4; ++r) {
      float vn0 = __fadd_rn(v0, __fmul_rn(k, __fsub_rn(xa[r], v0)));
      float vn1 = __fadd_rn(v1, __fmul_rn(k, __fsub_rn(xb[r], v1)));
      bool s0 = vn0 > vt;
      bool s1 = vn1 > vt;
      v0 = s0 ? 0.0f : vn0;   // exact reset to +0
      v1 = s1 ? 0.0f : vn1;
      if (MAIN) {
        unsigned long long u0 = __ballot(s0);
        unsigned long long u1 = __ballot(s1);
        const int t = g * 4 + r;            // compile-time after unroll
        m0 = (tt == t) ? (unsigned)u0 : m0;          // chunk cBase+0
        m1 = (tt == t) ? (unsigned)u1 : m1;          // chunk cBase+1
        m2 = (tt == t) ? (unsigned)(u0 >> 32) : m2;  // chunk cBase+2
        m3 = (tt == t) ? (unsigned)(u1 >> 32) : m3;  // chunk cBase+3
      }
    }
  }
}

__device__ __forceinline__ float lut_sum(unsigned m, const float* lut, int o, float bias) {
  float acc = bias;
#pragma unroll
  for (int g = 0; g < 6; ++g) {
    unsigned val = (m >> (5 * g)) & 31u;
    acc += lut[(g * 2 + o) * 32 + val];
  }
  return acc;
}

__global__ __launch_bounds__(64, 4) void lif_async(
    const float* __restrict__ x,      // (B, F, T)
    const float* __restrict__ tau,    // (3)
    const float* __restrict__ vth,    // (3)
    const float* __restrict__ convw,  // (3)
    const float* __restrict__ convb,  // (1)
    const float* __restrict__ linw,   // (2,10)
    const float* __restrict__ linb,   // (2)
    float* __restrict__ out)          // (B, 2, T)
{
  const int b    = blockIdx.x;
  const int cb   = blockIdx.y;       // chunks 4cb .. 4cb+3
  const int lane = threadIdx.x;
  const int half = lane >> 5;
  const int j    = lane & 31;
  const bool active = j < 30;
  const int c = active ? j / NF : 0;
  const int f = active ? j % NF : 0;

  __shared__ __align__(16) float xs[2 * BUFW];   // 10.24 KB double-buffered staging
  __shared__ float lut[384];                     // conv+linear LUT (single wave: no barrier)

  // LUT[g][o][val] = sum over set bits p of val of convw[(5g+p)/10]*linw[o,(5g+p)%10]
#pragma unroll
  for (int e = 0; e < 6; ++e) {
    int id = lane + 64 * e;
    int g = id >> 6, rem = id & 63, oo = rem >> 5, val = rem & 31;
    float sacc = 0.0f;
#pragma unroll
    for (int p = 0; p < 5; ++p) {
      if (val & (1 << p)) {
        int jj = 5 * g + p;
        sacc += convw[jj / NF] * linw[oo * NF + (jj % NF)];
      }
    }
    lut[id] = sacc;
  }

  const float k  = __fmul_rn(0.001f, tau[c]);
  const float vt = active ? vth[c] : 3.0e38f;   // inactive lanes never spike
  const int cBase = cb * CPB;

  // loader pointers: slot q=i*64+lane -> stream s=q>>3, global piece g=(q&7)^(s&7)
  const float* gm[5];   // main base: xrow + (t0 - WARM) + g*4 ; main stage S: +S*32
  const float* gw[5];   // warm base (chunk 0 clamped to row start)
#pragma unroll
  for (int i = 0; i < 5; ++i) {
    int q  = i * 64 + lane;
    int s  = q >> 3;
    int gg = (q & 7) ^ (s & 7);
    int qq = s / NF;
    int fL = s - qq * NF;
    int chunk = cBase + qq;
    int t0 = chunk * CHUNK;
    gm[i] = x + ((size_t)b * NF + fL) * (size_t)T_LEN + (t0 - WARM) + gg * 4;
    gw[i] = gm[i] + ((chunk == 0) ? WARM : 0);
  }

  // sim read bases: chain A = chunk cBase+2h (stream sA), chain B = +1 (stream sB)
  const int sA = half * 20 + f;
  const int sB = sA + 10;
  const float* pA0 = xs + sA * 32;  const float* pA1 = pA0 + BUFW;
  const float* pB0 = xs + sB * 32;  const float* pB1 = pB0 + BUFW;
  const int fxA = (sA & 7) << 2;
  const int fxB = (sB & 7) << 2;

  // epilogue role: lane = (o, tt)
  const int o  = half;
  const int tt = j;
  float wsum = 0.0f;
#pragma unroll
  for (int f2 = 0; f2 < NF; ++f2) wsum += linw[o * NF + f2];
  const float bias = linb[o] + convb[0] * wsum;
  float* ob = out + ((size_t)b * 2 + o) * T_LEN + cBase * CHUNK + tt;

  float v0 = 0.0f, v1 = 0.0f;
  unsigned m0 = 0, m1 = 0, m2 = 0, m3 = 0;
  float res[4][4];

  // ================= pipeline (vm queue: loads only; waits are exact) ============
  stage_loads(gw[0],      gw[1],      gw[2],      gw[3],      gw[4],      xs);         // L0 -> b0
  stage_loads(gw[0] + 32, gw[1] + 32, gw[2] + 32, gw[3] + 32, gw[4] + 32, xs + BUFW);  // L1 -> b1
  waitvm<5>();   // L0 done
  run32<false>(pA0, pB0, fxA, fxB, k, vt, tt, v0, v1, m0, m1, m2, m3);     // warm S0

  stage_loads(gw[0] + 64, gw[1] + 64, gw[2] + 64, gw[3] + 64, gw[4] + 64, xs);         // L2 -> b0
  waitvm<5>();   // L1 done
  run32<false>(pA1, pB1, fxA, fxB, k, vt, tt, v0, v1, m0, m1, m2, m3);     // warm S1

  stage_loads(gw[0] + 96, gw[1] + 96, gw[2] + 96, gw[3] + 96, gw[4] + 96, xs + BUFW);  // L3 -> b1
  waitvm<5>();   // L2 done
  run32<false>(pA0, pB0, fxA, fxB, k, vt, tt, v0, v1, m0, m1, m2, m3);     // warm S2

  stage_loads(gm[0] + 128, gm[1] + 128, gm[2] + 128, gm[3] + 128, gm[4] + 128, xs);    // L4 -> b0 (t0)
  waitvm<5>();   // L3 done
  run32<false>(pA1, pB1, fxA, fxB, k, vt, tt, v0, v1, m0, m1, m2, m3);     // warm S3

  if ((cb | half) == 0) v0 = 0.0f;   // chunk 0's true initial state

  stage_loads(gm[0] + 160, gm[1] + 160, gm[2] + 160, gm[3] + 160, gm[4] + 160, xs + BUFW); // L5 -> b1
  waitvm<5>();   // L4 done
  run32<true>(pA0, pB0, fxA, fxB, k, vt, tt, v0, v1, m0, m1, m2, m3);      // main w0
  res[0][0] = lut_sum(m0, lut, o, bias); res[0][1] = lut_sum(m1, lut, o, bias);
  res[0][2] = lut_sum(m2, lut, o, bias); res[0][3] = lut_sum(m3, lut, o, bias);

  stage_loads(gm[0] + 192, gm[1] + 192, gm[2] + 192, gm[3] + 192, gm[4] + 192, xs);    // L6 -> b0
  waitvm<5>();   // L5 done
  run32<true>(pA1, pB1, fxA, fxB, k, vt, tt, v0, v1, m0, m1, m2, m3);      // main w1
  res[1][0] = lut_sum(m0, lut, o, bias); res[1][1] = lut_sum(m1, lut, o, bias);
  res[1][2] = lut_sum(m2, lut, o, bias); res[1][3] = lut_sum(m3, lut, o, bias);

  stage_loads(gm[0] + 224, gm[1] + 224, gm[2] + 224, gm[3] + 224, gm[4] + 224, xs + BUFW); // L7 -> b1
  waitvm<5>();   // L6 done
  run32<true>(pA0, pB0, fxA, fxB, k, vt, tt, v0, v1, m0, m1, m2, m3);      // main w2
  res[2][0] = lut_sum(m0, lut, o, bias); res[2][1] = lut_sum(m1, lut, o, bias);
  res[2][2] = lut_sum(m2, lut, o, bias); res[2][3] = lut_sum(m3, lut, o, bias);

  waitvm<0>();   // L7 done
  run32<true>(pA1, pB1, fxA, fxB, k, vt, tt, v0, v1, m0, m1, m2, m3);      // main w3
  res[3][0] = lut_sum(m0, lut, o, bias); res[3][1] = lut_sum(m1, lut, o, bias);
  res[3][2] = lut_sum(m2, lut, o, bias); res[3][3] = lut_sum(m3, lut, o, bias);

  // coalesced stores, once
#pragma unroll
  for (int w = 0; w < 4; ++w)
#pragma unroll
    for (int q = 0; q < 4; ++q)
      ob[q * CHUNK + w * 32] = res[w][q];
}

extern "C" void kernel_launch(void* const* d_in, const int* in_sizes, int n_in,
                              void* d_out, int out_size, void* d_ws, size_t ws_size,
                              hipStream_t stream) {
  const float* x     = (const float*)d_in[0];
  const float* tau   = (const float*)d_in[1];
  const float* vthp  = (const float*)d_in[2];
  const float* convw = (const float*)d_in[3];
  const float* convb = (const float*)d_in[4];
  const float* linw  = (const float*)d_in[5];
  const float* linb  = (const float*)d_in[6];
  float* out = (float*)d_out;

  const int B = in_sizes[0] / (NF * T_LEN);  // 256
  lif_async<<<dim3(B, GRIDY), dim3(64), 0, stream>>>(
      x, tau, vthp, convw, convb, linw, linb, out);
}